// Round 2
// baseline (2911.183 us; speedup 1.0000x reference)
//
#include <hip/hip_runtime.h>
#include <hip/hip_bf16.h>
#include <math.h>

#define HID 4096
#define DH  128
#define NQH 32
#define NKVH 8
#define BB  2
#define TQ  2048
#define BT  (BB*TQ)

typedef __bf16 bf16x8 __attribute__((ext_vector_type(8)));
typedef __bf16 bf16x4 __attribute__((ext_vector_type(4)));
typedef float  f32x4  __attribute__((ext_vector_type(4)));

#define MFMA(a,b,c) __builtin_amdgcn_mfma_f32_16x16x32_bf16(a,b,c,0,0,0)

// ---------------------------------------------------------------------------
// QKV GEMM: fp32 x [16 x HID] @ fp32 W[:, head-slice 128] -> bf16, per block.
// 8 waves, BK=64.  Epilogue: Q/K -> RMSnorm + RoPE -> qb/kb [b][h][t][d];
// V -> vt [b][h][d][t] (transposed for the PV B-fragment).
// ---------------------------------------------------------------------------
__global__ __launch_bounds__(512) void qkv_kernel(
    const float* __restrict__ x,  const float* __restrict__ wq,
    const float* __restrict__ wk, const float* __restrict__ wv,
    const float* __restrict__ qnw, const float* __restrict__ knw,
    __bf16* __restrict__ qb, __bf16* __restrict__ kb, __bf16* __restrict__ vt)
{
    const int rt   = blockIdx.x;          // row tile (16 tokens)
    const int ht   = blockIdx.y;          // 0..31 Q heads, 32..39 K, 40..47 V
    const int tid  = threadIdx.x;
    const int wave = tid >> 6;
    const int lane = tid & 63;
    const int m16  = lane & 15;
    const int quad = lane >> 4;

    const float* W; int Ncols, kind, hsel;
    if (ht < NQH)             { W = wq; Ncols = NQH*DH;  hsel = ht;            kind = 0; }
    else if (ht < NQH+NKVH)   { W = wk; Ncols = NKVH*DH; hsel = ht-NQH;        kind = 1; }
    else                      { W = wv; Ncols = NKVH*DH; hsel = ht-NQH-NKVH;   kind = 2; }
    const int col0 = hsel * DH;

    __shared__ alignas(16) __bf16 As[16][72];    // A tile (bf16), padded
    __shared__ alignas(16) __bf16 Bs[128][72];   // W tile transposed [n][k], xor-swizzled
    __shared__ float Ct[16][132];                // fp32 result tile for epilogue

    const int row0 = rt << 4;
    f32x4 acc = {0.f,0.f,0.f,0.f};

    const int arow = tid >> 5, acol = (tid & 31) << 1;
    const int nn   = (tid & 15) << 3;                 // n-base this thread writes
    const int X    = ((wave << 1) + (m16 >> 3)) & 7;  // read-side swizzle

    for (int k0 = 0; k0 < HID; k0 += 64) {
        // stage A: 16x64 fp32 -> bf16, 2 floats per thread
        const float2 xv = *(const float2*)(x + (size_t)(row0 + arow)*HID + k0 + acol);
        As[arow][acol]     = (__bf16)xv.x;
        As[arow][acol + 1] = (__bf16)xv.y;
        // stage B: 64x128 fp32 -> bf16, transposed scalar LDS store (swizzled)
        #pragma unroll
        for (int p = 0; p < 2; ++p) {
            const int kk = ((p << 9) + tid) >> 4;     // 0..63
            const float4 w0 = *(const float4*)(W + (size_t)(k0 + kk)*Ncols + col0 + nn);
            const float4 w1 = *(const float4*)(W + (size_t)(k0 + kk)*Ncols + col0 + nn + 4);
            const int c = (((kk >> 3) ^ ((nn >> 3) & 7)) << 3) + (kk & 7);
            Bs[nn+0][c] = (__bf16)w0.x; Bs[nn+1][c] = (__bf16)w0.y;
            Bs[nn+2][c] = (__bf16)w0.z; Bs[nn+3][c] = (__bf16)w0.w;
            Bs[nn+4][c] = (__bf16)w1.x; Bs[nn+5][c] = (__bf16)w1.y;
            Bs[nn+6][c] = (__bf16)w1.z; Bs[nn+7][c] = (__bf16)w1.w;
        }
        __syncthreads();
        #pragma unroll
        for (int ka = 0; ka < 64; ka += 32) {
            bf16x8 a = *(const bf16x8*)&As[m16][ka + (quad << 3)];
            const int kb8 = (ka >> 3) + quad;
            bf16x8 b = *(const bf16x8*)&Bs[(wave << 4) + m16][(kb8 ^ X) << 3];
            acc = MFMA(a, b, acc);
        }
        __syncthreads();
    }

    #pragma unroll
    for (int r = 0; r < 4; ++r)
        Ct[(quad << 2) + r][(wave << 4) + m16] = acc[r];
    __syncthreads();

    const int bidx = row0 >> 11;          // batch (16-row tile never crosses batch)
    if (kind == 2) {
        // V: transposed store [b][hkv][d][t], 4 consecutive t per thread
        const int d  = tid >> 2;
        const int ts = (tid & 3) << 2;
        const int tpos = (row0 & (TQ-1)) + ts;
        bf16x4 o;
        #pragma unroll
        for (int i = 0; i < 4; ++i) o[i] = (__bf16)Ct[ts + i][d];
        *(bf16x4*)(vt + ((size_t)(bidx*NKVH + hsel)*DH + d)*TQ + tpos) = o;
    } else {
        // Q/K: RMS norm over 128 then RoPE
        const int row = tid >> 5;
        const int c0  = (tid & 31) << 2;
        float v[4]; float ss = 0.f;
        #pragma unroll
        for (int i = 0; i < 4; ++i) { v[i] = Ct[row][c0 + i]; ss += v[i]*v[i]; }
        #pragma unroll
        for (int off = 16; off > 0; off >>= 1) ss += __shfl_xor(ss, off);
        const float inv = rsqrtf(ss * (1.0f/DH) + 1e-6f);
        const float* nw = kind ? knw : qnw;
        const int tpos = (row0 & (TQ-1)) + row;
        bf16x4 o;
        #pragma unroll
        for (int i = 0; i < 4; ++i) {
            const int c = c0 + i;
            const float nv = nw[c]      * v[i]            * inv;
            const float pv = nw[c ^ 64] * Ct[row][c ^ 64] * inv;
            // timescale = THETA^(i/64); angle = t / timescale
            const float ang = (float)tpos * exp2f(-0.31143075895f * (float)(c & 63));
            float sn, cs; sincosf(ang, &sn, &cs);
            o[i] = (__bf16)((c < 64) ? (nv*cs - pv*sn) : (nv*cs + pv*sn));
        }
        __bf16* dst = (kind == 0)
            ? qb + ((size_t)(bidx*NQH  + hsel)*TQ + tpos)*DH + c0
            : kb + ((size_t)(bidx*NKVH + hsel)*TQ + tpos)*DH + c0;
        *(bf16x4*)dst = o;
    }
}

// ---------------------------------------------------------------------------
// Flash attention, causal, GQA. 1 wave per (b, h, 16-row Q tile). All bf16 in.
// ---------------------------------------------------------------------------
__global__ __launch_bounds__(64) void attn_kernel(
    const __bf16* __restrict__ qb, const __bf16* __restrict__ kb,
    const __bf16* __restrict__ vt, __bf16* __restrict__ ab)
{
    const int qt = blockIdx.x;
    const int bh = blockIdx.y;
    const int b = bh >> 5, h = bh & 31, hk = h >> 2;
    const int lane = threadIdx.x;
    const int m16 = lane & 15, quad = lane >> 4;

    const __bf16* qp = qb + (size_t)(b*NQH  + h )*TQ*DH;
    const __bf16* kp = kb + (size_t)(b*NKVH + hk)*TQ*DH;
    const __bf16* vp = vt + (size_t)(b*NKVH + hk)*DH*TQ;   // [d][t]

    const int q0 = qt << 4;
    bf16x8 aq[4];
    #pragma unroll
    for (int ks = 0; ks < 4; ++ks)
        aq[ks] = *(const bf16x8*)(qp + (size_t)(q0 + m16)*DH + (ks << 5) + (quad << 3));

    f32x4 o[8];
    #pragma unroll
    for (int cc = 0; cc < 8; ++cc) o[cc] = (f32x4){0.f,0.f,0.f,0.f};
    float mrow[4] = {-1e30f,-1e30f,-1e30f,-1e30f};
    float lrow[4] = {0.f,0.f,0.f,0.f};

    __shared__ alignas(16) __bf16 Pl[16][40];
    const float scale = 0.08838834764831845f;   // 1/sqrt(128)

    const int ktmax = (q0 + 15) >> 5;
    for (int kt = 0; kt <= ktmax; ++kt) {
        const int k0 = kt << 5;
        f32x4 s0 = {0.f,0.f,0.f,0.f}, s1 = {0.f,0.f,0.f,0.f};
        #pragma unroll
        for (int ks = 0; ks < 4; ++ks) {
            bf16x8 b0 = *(const bf16x8*)(kp + (size_t)(k0 + m16)*DH      + (ks << 5) + (quad << 3));
            bf16x8 b1 = *(const bf16x8*)(kp + (size_t)(k0 + 16 + m16)*DH + (ks << 5) + (quad << 3));
            s0 = MFMA(aq[ks], b0, s0);
            s1 = MFMA(aq[ks], b1, s1);
        }
        float alpha[4];
        #pragma unroll
        for (int r = 0; r < 4; ++r) {
            const int qg = q0 + (quad << 2) + r;
            const int kg = k0 + m16;
            float a_ = (kg      <= qg) ? s0[r]*scale : -1e30f;
            float b_ = (kg + 16 <= qg) ? s1[r]*scale : -1e30f;
            float t = fmaxf(a_, b_);
            t = fmaxf(t, __shfl_xor(t, 1)); t = fmaxf(t, __shfl_xor(t, 2));
            t = fmaxf(t, __shfl_xor(t, 4)); t = fmaxf(t, __shfl_xor(t, 8));
            const float mn = fmaxf(mrow[r], t);
            alpha[r] = __expf(mrow[r] - mn);
            const float p0 = __expf(a_ - mn);
            const float p1 = __expf(b_ - mn);
            float rs = p0 + p1;
            rs += __shfl_xor(rs, 1); rs += __shfl_xor(rs, 2);
            rs += __shfl_xor(rs, 4); rs += __shfl_xor(rs, 8);
            lrow[r] = lrow[r]*alpha[r] + rs;
            mrow[r] = mn;
            Pl[(quad << 2) + r][m16]      = (__bf16)p0;
            Pl[(quad << 2) + r][m16 + 16] = (__bf16)p1;
        }
        __syncthreads();
        const bf16x8 pf = *(const bf16x8*)&Pl[m16][quad << 3];
        #pragma unroll
        for (int cc = 0; cc < 8; ++cc) {
            #pragma unroll
            for (int r = 0; r < 4; ++r) o[cc][r] *= alpha[r];
            bf16x8 vf = *(const bf16x8*)(vp + (size_t)((cc << 4) + m16)*TQ + k0 + (quad << 3));
            o[cc] = MFMA(pf, vf, o[cc]);
        }
        __syncthreads();
    }

    #pragma unroll
    for (int r = 0; r < 4; ++r) {
        const int t = q0 + (quad << 2) + r;
        const float invl = 1.0f / lrow[r];
        __bf16* dst = ab + (size_t)(b*TQ + t)*(NQH*DH) + h*DH + m16;
        #pragma unroll
        for (int cc = 0; cc < 8; ++cc)
            dst[cc << 4] = (__bf16)(o[cc][r] * invl);
    }
}

// ---------------------------------------------------------------------------
// Output GEMM: ab(bf16)[BT x 4096] @ wo(fp32->bf16)[4096 x 4096] -> out fp32
// ---------------------------------------------------------------------------
__global__ __launch_bounds__(512) void ogemm_kernel(
    const __bf16* __restrict__ Am, const float* __restrict__ W,
    float* __restrict__ out)
{
    const int rt = blockIdx.x;
    const int ct = blockIdx.y;
    const int tid = threadIdx.x;
    const int wave = tid >> 6;
    const int lane = tid & 63;
    const int m16 = lane & 15;
    const int quad = lane >> 4;
    const int col0 = ct << 7;

    __shared__ alignas(16) __bf16 As[16][72];
    __shared__ alignas(16) __bf16 Bs[128][72];
    __shared__ float Ct[16][132];

    const int row0 = rt << 4;
    f32x4 acc = {0.f,0.f,0.f,0.f};
    const int arow = tid >> 5, acol = (tid & 31) << 1;
    const int nn = (tid & 15) << 3;
    const int X = ((wave << 1) + (m16 >> 3)) & 7;

    for (int k0 = 0; k0 < HID; k0 += 64) {
        // A is bf16 already: 1 dword = 2 elems per thread
        *(unsigned int*)&As[arow][acol] =
            *(const unsigned int*)(Am + (size_t)(row0 + arow)*HID + k0 + acol);
        #pragma unroll
        for (int p = 0; p < 2; ++p) {
            const int kk = ((p << 9) + tid) >> 4;
            const float4 w0 = *(const float4*)(W + (size_t)(k0 + kk)*HID + col0 + nn);
            const float4 w1 = *(const float4*)(W + (size_t)(k0 + kk)*HID + col0 + nn + 4);
            const int c = (((kk >> 3) ^ ((nn >> 3) & 7)) << 3) + (kk & 7);
            Bs[nn+0][c] = (__bf16)w0.x; Bs[nn+1][c] = (__bf16)w0.y;
            Bs[nn+2][c] = (__bf16)w0.z; Bs[nn+3][c] = (__bf16)w0.w;
            Bs[nn+4][c] = (__bf16)w1.x; Bs[nn+5][c] = (__bf16)w1.y;
            Bs[nn+6][c] = (__bf16)w1.z; Bs[nn+7][c] = (__bf16)w1.w;
        }
        __syncthreads();
        #pragma unroll
        for (int ka = 0; ka < 64; ka += 32) {
            bf16x8 a = *(const bf16x8*)&As[m16][ka + (quad << 3)];
            const int kb8 = (ka >> 3) + quad;
            bf16x8 b = *(const bf16x8*)&Bs[(wave << 4) + m16][(kb8 ^ X) << 3];
            acc = MFMA(a, b, acc);
        }
        __syncthreads();
    }
    #pragma unroll
    for (int r = 0; r < 4; ++r)
        Ct[(quad << 2) + r][(wave << 4) + m16] = acc[r];
    __syncthreads();
    const int row = tid >> 5, c0 = (tid & 31) << 2;
    const float4 o = *(const float4*)&Ct[row][c0];
    *(float4*)(out + (size_t)(row0 + row)*HID + col0 + c0) = o;
}

extern "C" void kernel_launch(void* const* d_in, const int* in_sizes, int n_in,
                              void* d_out, int out_size, void* d_ws, size_t ws_size,
                              hipStream_t stream)
{
    const float* x   = (const float*)d_in[0];
    const float* wq  = (const float*)d_in[1];
    const float* wk  = (const float*)d_in[2];
    const float* wv  = (const float*)d_in[3];
    const float* wo  = (const float*)d_in[4];
    const float* qnw = (const float*)d_in[5];
    const float* knw = (const float*)d_in[6];
    float* out = (float*)d_out;

    // qb (bf16, 33.5 MB) lives in the first half of d_out (fp32, 67 MB):
    // attn reads it strictly before ogemm overwrites out (stream order).
    __bf16* qb = (__bf16*)d_out;                      // [B][32][T][128]  33.5 MB
    __bf16* kb = (__bf16*)d_ws;                       // [B][8][T][128]    8.4 MB
    __bf16* vt = kb + (size_t)BB*NKVH*TQ*DH;          // [B][8][128][T]    8.4 MB
    __bf16* ab = vt + (size_t)BB*NKVH*TQ*DH;          // [B][T][4096]     33.5 MB
    const size_t need = ((size_t)BB*NKVH*TQ*DH*2 + (size_t)BB*TQ*NQH*DH)*sizeof(__bf16);
    if (ws_size < need) return;   // deterministic no-op -> diagnosable absmax

    qkv_kernel<<<dim3(BT/16, NQH + 2*NKVH), 512, 0, stream>>>(
        x, wq, wk, wv, qnw, knw, qb, kb, vt);
    attn_kernel<<<dim3(TQ/16, BB*NQH), 64, 0, stream>>>(qb, kb, vt, ab);
    ogemm_kernel<<<dim3(BT/16, HID/128), 512, 0, stream>>>(ab, wo, out);
}